// Round 14
// baseline (248.068 us; speedup 1.0000x reference)
//
#include <hip/hip_runtime.h>
#include <hip/hip_bf16.h>

#define DIV_UP(a, b) (((a) + (b) - 1) / (b))
typedef long long ll;
typedef __attribute__((ext_vector_type(8))) short short8;
typedef __attribute__((ext_vector_type(4))) float f32x4;

// ---------- runtime-dtype helpers ----------
__device__ __forceinline__ float ldf(const void* p, ll i, int bf) {
    return bf ? __bfloat162float(((const __hip_bfloat16*)p)[i]) : ((const float*)p)[i];
}
__device__ __forceinline__ int ldi(const int* p, ll i, int w) {
    return w ? p[2 * i] : p[i];
}
// decode packed bf16 pair (little-endian: low 16 bits = even col)
__device__ __forceinline__ void bf16pair(unsigned u, float& f0, float& f1) {
    f0 = __uint_as_float(u << 16);
    f1 = __uint_as_float(u & 0xFFFF0000u);
}

// ---- ordered-uint encoding for float atomicMax ----
__device__ __forceinline__ unsigned fenc(float f) {
    unsigned u = __float_as_uint(f);
    return (u & 0x80000000u) ? ~u : (u | 0x80000000u);
}
__device__ __forceinline__ float fdec(unsigned u) {
    unsigned v = (u & 0x80000000u) ? (u & 0x7FFFFFFFu) : ~u;
    return __uint_as_float(v);
}
#define ENC_NEG_INF 0x007FFFFFu

// ---- f32 misc pool offsets ----
#define MB1 0    // b1: 75
#define MB2 80   // b2: 150
#define MHW 240  // Wo: 150
#define MB3 390  // b3: 50
#define MBO 440  // bo: 3
#define N_MISC 444
// ---- Wpack (bf16, B-fragment layout) region bases, in bf16 elements ----
#define P1 0      // L1: CT=5, KC=2 -> 5120
#define P2 5120   // L2: CT=10, KC=3 -> 15360
#define P3 20480  // L3: CT=4, KC=5 -> 10240
#define N_PACK 30720

// ---------------- dtype detection + cnt zero + pooled init (fused, grid-wide) --------------
__global__ void k_detect(const unsigned* __restrict__ xb, const unsigned* __restrict__ eb,
                         int* __restrict__ flags, int* __restrict__ cnt,
                         unsigned* __restrict__ pooled, int N) {
    int idx = blockIdx.x * 256 + threadIdx.x;
    if (idx < N) cnt[idx] = 0;
    if (blockIdx.x == 1) {
        if (threadIdx.x < 192) pooled[threadIdx.x] = ENC_NEG_INF;
        return;
    }
    if (blockIdx.x != 0) return;
    __shared__ int sv[2];
    int t = threadIdx.x;
    if (t < 2) sv[t] = 0;
    __syncthreads();
    unsigned e = (xb[t] >> 7) & 0xFFu;
    int vote = (e >= 115u && e <= 133u) ? 1 : 0;
    int zero = (eb[2 * t + 1] == 0u) ? 1 : 0;
    atomicAdd(&sv[0], vote);
    atomicAdd(&sv[1], zero);
    __syncthreads();
    if (t == 0) {
        flags[0] = (sv[0] > 128) ? 1 : 0;
        flags[1] = (sv[1] > 200) ? 1 : 0;
    }
}

// ---------------- weight conversion: MFMA B-fragment pack + misc f32 pool (fused) ---------
__global__ void k_cvt(const void* __restrict__ W1, const void* __restrict__ b1,
                      const void* __restrict__ W2, const void* __restrict__ b2,
                      const void* __restrict__ W3, const void* __restrict__ b3,
                      const void* __restrict__ Wo, const void* __restrict__ bo,
                      __hip_bfloat16* __restrict__ wp, float* __restrict__ wfm,
                      const int* __restrict__ flags) {
    int t = blockIdx.x * blockDim.x + threadIdx.x;
    int bf = flags[0];
    if (t < N_PACK) {
        const void* W;
        int i, K, OUT, KC;
        if (t < P2) {
            W = W1;
            i = t;
            K = 36;
            OUT = 75;
            KC = 2;
        } else if (t < P3) {
            W = W2;
            i = t - P2;
            K = 75;
            OUT = 150;
            KC = 3;
        } else {
            W = W3;
            i = t - P3;
            K = 150;
            OUT = 50;
            KC = 5;
        }
        int j = i & 7;
        int lane = (i >> 3) & 63;
        int tile = i >> 9;
        int kc = tile % KC;
        int ct = tile / KC;
        int k = kc * 32 + ((lane >> 4) << 3) + j;
        int col = ct * 16 + (lane & 15);
        float v = (k < K && col < OUT) ? ldf(W, (ll)k * OUT + col, bf) : 0.0f;
        wp[t] = __float2bfloat16(v);
    } else {
        int m = t - N_PACK;
        if (m >= N_MISC) return;
        float v = 0.0f;
        if (m < 75)
            v = ldf(b1, m, bf);
        else if (m >= MB2 && m < MB2 + 150)
            v = ldf(b2, m - MB2, bf);
        else if (m >= MHW && m < MHW + 150)
            v = ldf(Wo, m - MHW, bf);
        else if (m >= MB3 && m < MB3 + 50)
            v = ldf(b3, m - MB3, bf);
        else if (m >= MBO && m < MBO + 3)
            v = ldf(bo, m - MBO, bf);
        wfm[m] = v;
    }
}

// ---------------- CSR build ----------------
__global__ void k_hist(const int* __restrict__ ei, int* __restrict__ cnt,
                       const int* __restrict__ flags, int E) {
    int t = blockIdx.x * blockDim.x + threadIdx.x;
    if (t >= E) return;
    atomicAdd(&cnt[ldi(ei, (ll)E + t, flags[1])], 1);
}
__global__ void k_scan1(const int* __restrict__ cnt, int* __restrict__ bsum,
                        float* __restrict__ dinv, int N) {
    __shared__ int s[256];
    int t = threadIdx.x;
    int idx = blockIdx.x * 256 + t;
    int v = (idx < N) ? cnt[idx] : 0;
    if (idx < N) dinv[idx] = rsqrtf((float)v + 1.0f);  // +1 self-loop
    s[t] = v;
    __syncthreads();
#pragma unroll
    for (int off = 128; off > 0; off >>= 1) {
        if (t < off) s[t] += s[t + off];
        __syncthreads();
    }
    if (t == 0) bsum[blockIdx.x] = s[0];
}
// per-block: computes its own global offset from bsum (NB <= 256), local scan of cnt ->
// rowptr; re-zeroes cnt for use as k_fill cursor. Replaces the old serial k_scan2 launch.
__global__ void k_scan3(int* __restrict__ cnt, const int* __restrict__ bsum,
                        int* __restrict__ rowptr, int nb, int N) {
    __shared__ int s[256];
    int t = threadIdx.x;
    // offset = sum of bsum[i] for i < blockIdx.x  (nb <= 256)
    s[t] = (t < blockIdx.x && t < nb) ? bsum[t] : 0;
    __syncthreads();
#pragma unroll
    for (int off = 128; off > 0; off >>= 1) {
        if (t < off) s[t] += s[t + off];
        __syncthreads();
    }
    int offset = s[0];
    __syncthreads();
    int idx = blockIdx.x * 256 + t;
    int v = (idx < N) ? cnt[idx] : 0;
    if (idx < N) cnt[idx] = 0;
    s[t] = v;
    __syncthreads();
    for (int off = 1; off < 256; off <<= 1) {
        int o = (t >= off) ? s[t - off] : 0;
        __syncthreads();
        s[t] += o;
        __syncthreads();
    }
    if (idx <= N) rowptr[idx] = offset + s[t] - v;
}
__global__ void k_fill(const int* __restrict__ ei, const int* __restrict__ rowptr,
                       int* __restrict__ cursor, int2* __restrict__ ep,
                       const float* __restrict__ dinv, const int* __restrict__ flags, int E) {
    int t = blockIdx.x * blockDim.x + threadIdx.x;
    if (t >= E) return;
    int wi = flags[1];
    int s = ldi(ei, t, wi);
    int d = ldi(ei, (ll)E + t, wi);
    int pos = rowptr[d] + atomicAdd(&cursor[d], 1);
    int2 v;
    v.x = s;
    v.y = __float_as_int(dinv[s] * dinv[d]);
    ep[pos] = v;
}

// ---------------- layer-1 aggregation: TWO nodes per wave (half-wave = 32 lanes) ----------
__global__ void k_agg1(const void* __restrict__ X, __hip_bfloat16* __restrict__ Y,
                       const int* __restrict__ rowptr, const int2* __restrict__ ep,
                       const float* __restrict__ dinv, const int* __restrict__ flags, int N) {
    int n = blockIdx.x * 8 + (threadIdx.x >> 5);
    if (n >= N) return;
    int lane = threadIdx.x & 31;
    int bf = flags[0];
    float di = dinv[n];
    float w0 = di * di;
    int j = rowptr[n];
    int je = rowptr[n + 1];
    if (bf) {
        const __hip_bfloat16* Xb = (const __hip_bfloat16*)X;
        bool act = lane < 18;
        float a0 = 0.0f, a1 = 0.0f;
        if (act) {
            float f0, f1;
            bf16pair(*(const unsigned*)(Xb + (ll)n * 36 + 2 * lane), f0, f1);
            a0 = w0 * f0;
            a1 = w0 * f1;
        }
        for (; j + 3 < je; j += 4) {
            int2 v0 = ep[j];
            int2 v1 = ep[j + 1];
            int2 v2 = ep[j + 2];
            int2 v3 = ep[j + 3];
            if (act) {
                float f0, f1;
                bf16pair(*(const unsigned*)(Xb + (ll)v0.x * 36 + 2 * lane), f0, f1);
                float wa = __int_as_float(v0.y);
                a0 = fmaf(wa, f0, a0);
                a1 = fmaf(wa, f1, a1);
                bf16pair(*(const unsigned*)(Xb + (ll)v1.x * 36 + 2 * lane), f0, f1);
                wa = __int_as_float(v1.y);
                a0 = fmaf(wa, f0, a0);
                a1 = fmaf(wa, f1, a1);
                bf16pair(*(const unsigned*)(Xb + (ll)v2.x * 36 + 2 * lane), f0, f1);
                wa = __int_as_float(v2.y);
                a0 = fmaf(wa, f0, a0);
                a1 = fmaf(wa, f1, a1);
                bf16pair(*(const unsigned*)(Xb + (ll)v3.x * 36 + 2 * lane), f0, f1);
                wa = __int_as_float(v3.y);
                a0 = fmaf(wa, f0, a0);
                a1 = fmaf(wa, f1, a1);
            }
        }
        for (; j < je; ++j) {
            int2 v0 = ep[j];
            if (act) {
                float f0, f1;
                bf16pair(*(const unsigned*)(Xb + (ll)v0.x * 36 + 2 * lane), f0, f1);
                float wa = __int_as_float(v0.y);
                a0 = fmaf(wa, f0, a0);
                a1 = fmaf(wa, f1, a1);
            }
        }
        if (act) {
            __hip_bfloat162 h;
            h.x = __float2bfloat16(a0);
            h.y = __float2bfloat16(a1);
            *(__hip_bfloat162*)(Y + (ll)n * 64 + 2 * lane) = h;
        }
    } else {
        const float* Xf = (const float*)X;
        bool act2 = lane < 4;
        float a0 = w0 * Xf[(ll)n * 36 + lane];
        float a1 = act2 ? w0 * Xf[(ll)n * 36 + 32 + lane] : 0.0f;
        for (; j + 3 < je; j += 4) {
            int2 v0 = ep[j];
            int2 v1 = ep[j + 1];
            int2 v2 = ep[j + 2];
            int2 v3 = ep[j + 3];
            float wa = __int_as_float(v0.y);
            a0 = fmaf(wa, Xf[(ll)v0.x * 36 + lane], a0);
            if (act2) a1 = fmaf(wa, Xf[(ll)v0.x * 36 + 32 + lane], a1);
            wa = __int_as_float(v1.y);
            a0 = fmaf(wa, Xf[(ll)v1.x * 36 + lane], a0);
            if (act2) a1 = fmaf(wa, Xf[(ll)v1.x * 36 + 32 + lane], a1);
            wa = __int_as_float(v2.y);
            a0 = fmaf(wa, Xf[(ll)v2.x * 36 + lane], a0);
            if (act2) a1 = fmaf(wa, Xf[(ll)v2.x * 36 + 32 + lane], a1);
            wa = __int_as_float(v3.y);
            a0 = fmaf(wa, Xf[(ll)v3.x * 36 + lane], a0);
            if (act2) a1 = fmaf(wa, Xf[(ll)v3.x * 36 + 32 + lane], a1);
        }
        for (; j < je; ++j) {
            int2 v0 = ep[j];
            float wa = __int_as_float(v0.y);
            a0 = fmaf(wa, Xf[(ll)v0.x * 36 + lane], a0);
            if (act2) a1 = fmaf(wa, Xf[(ll)v0.x * 36 + 32 + lane], a1);
        }
        Y[(ll)n * 64 + lane] = __float2bfloat16(a0);
        if (act2) Y[(ll)n * 64 + 32 + lane] = __float2bfloat16(a1);
    }
}

// ---------------- layer-2 paired aggregation: TWO nodes per wave ----------------
__global__ void k_aggp2(const __hip_bfloat16* __restrict__ X, int xs,
                        __hip_bfloat16* __restrict__ Y, int ys, const int* __restrict__ rowptr,
                        const int2* __restrict__ ep, const float* __restrict__ dinv, int N) {
    int n = blockIdx.x * 8 + (threadIdx.x >> 5);
    if (n >= N) return;
    int lane = threadIdx.x & 31;
    bool act2 = lane < 6;  // pairs 32..37
    float di = dinv[n];
    float w0 = di * di;
    float a0, a1, b0 = 0.0f, b1 = 0.0f;
    {
        float f0, f1;
        bf16pair(*(const unsigned*)(X + (ll)n * xs + 2 * lane), f0, f1);
        a0 = w0 * f0;
        a1 = w0 * f1;
        if (act2) {
            bf16pair(*(const unsigned*)(X + (ll)n * xs + 64 + 2 * lane), f0, f1);
            b0 = w0 * f0;
            b1 = w0 * f1;
        }
    }
    int j = rowptr[n];
    int je = rowptr[n + 1];
    for (; j + 1 < je; j += 2) {
        int2 v0 = ep[j];
        int2 v1 = ep[j + 1];
        float wa = __int_as_float(v0.y), wb = __int_as_float(v1.y);
        float f0, f1;
        bf16pair(*(const unsigned*)(X + (ll)v0.x * xs + 2 * lane), f0, f1);
        a0 = fmaf(wa, f0, a0);
        a1 = fmaf(wa, f1, a1);
        bf16pair(*(const unsigned*)(X + (ll)v1.x * xs + 2 * lane), f0, f1);
        a0 = fmaf(wb, f0, a0);
        a1 = fmaf(wb, f1, a1);
        if (act2) {
            bf16pair(*(const unsigned*)(X + (ll)v0.x * xs + 64 + 2 * lane), f0, f1);
            b0 = fmaf(wa, f0, b0);
            b1 = fmaf(wa, f1, b1);
            bf16pair(*(const unsigned*)(X + (ll)v1.x * xs + 64 + 2 * lane), f0, f1);
            b0 = fmaf(wb, f0, b0);
            b1 = fmaf(wb, f1, b1);
        }
    }
    if (j < je) {
        int2 v0 = ep[j];
        float wa = __int_as_float(v0.y);
        float f0, f1;
        bf16pair(*(const unsigned*)(X + (ll)v0.x * xs + 2 * lane), f0, f1);
        a0 = fmaf(wa, f0, a0);
        a1 = fmaf(wa, f1, a1);
        if (act2) {
            bf16pair(*(const unsigned*)(X + (ll)v0.x * xs + 64 + 2 * lane), f0, f1);
            b0 = fmaf(wa, f0, b0);
            b1 = fmaf(wa, f1, b1);
        }
    }
    __hip_bfloat162 h;
    h.x = __float2bfloat16(a0);
    h.y = __float2bfloat16(a1);
    *(__hip_bfloat162*)(Y + (ll)n * ys + 2 * lane) = h;
    if (act2) {
        h.x = __float2bfloat16(b0);
        h.y = __float2bfloat16(b1);
        *(__hip_bfloat162*)(Y + (ll)n * ys + 64 + 2 * lane) = h;
    }
}

// ---------------- fused layer-3 aggregation + head + segment-max pool ----------------
// TWO nodes per wave (half-wave = 32 lanes); z computed per node, pooled via block LDS
// lmax + global atomicMax flush. zbuf round-trip and k_pool launch eliminated (R14).
__global__ void k_agg3h(const __hip_bfloat16* __restrict__ X, int xs,
                        const int* __restrict__ rowptr, const int2* __restrict__ ep,
                        const float* __restrict__ dinv, const float* __restrict__ wfm,
                        const int* __restrict__ batch, unsigned* __restrict__ pooled,
                        const int* __restrict__ flags, int N) {
    __shared__ unsigned lmax[192];
    for (int i = threadIdx.x; i < 192; i += blockDim.x) lmax[i] = ENC_NEG_INF;
    __syncthreads();
    int n = blockIdx.x * 8 + (threadIdx.x >> 5);
    int lane = threadIdx.x & 31;
    bool valid = n < N;
    bool act = valid && lane < 25;
    int c0 = 2 * lane;
    float w00 = 0, w01 = 0, w02 = 0, w10 = 0, w11 = 0, w12 = 0, bb0 = 0, bb1 = 0;
    if (act) {
        w00 = wfm[MHW + c0 * 3 + 0];
        w01 = wfm[MHW + c0 * 3 + 1];
        w02 = wfm[MHW + c0 * 3 + 2];
        w10 = wfm[MHW + c0 * 3 + 3];
        w11 = wfm[MHW + c0 * 3 + 4];
        w12 = wfm[MHW + c0 * 3 + 5];
        bb0 = wfm[MB3 + c0];
        bb1 = wfm[MB3 + c0 + 1];
    }
    float a0 = 0.0f, a1 = 0.0f;
    if (act) {
        float di = dinv[n];
        float w0 = di * di;
        float f0, f1;
        bf16pair(*(const unsigned*)(X + (ll)n * xs + 2 * lane), f0, f1);
        a0 = w0 * f0;
        a1 = w0 * f1;
    }
    int j = valid ? rowptr[n] : 0;
    int je = valid ? rowptr[n + 1] : 0;
    for (; j + 3 < je; j += 4) {
        int2 v0 = ep[j];
        int2 v1 = ep[j + 1];
        int2 v2 = ep[j + 2];
        int2 v3 = ep[j + 3];
        if (act) {
            float f0, f1;
            bf16pair(*(const unsigned*)(X + (ll)v0.x * xs + 2 * lane), f0, f1);
            float wa = __int_as_float(v0.y);
            a0 = fmaf(wa, f0, a0);
            a1 = fmaf(wa, f1, a1);
            bf16pair(*(const unsigned*)(X + (ll)v1.x * xs + 2 * lane), f0, f1);
            wa = __int_as_float(v1.y);
            a0 = fmaf(wa, f0, a0);
            a1 = fmaf(wa, f1, a1);
            bf16pair(*(const unsigned*)(X + (ll)v2.x * xs + 2 * lane), f0, f1);
            wa = __int_as_float(v2.y);
            a0 = fmaf(wa, f0, a0);
            a1 = fmaf(wa, f1, a1);
            bf16pair(*(const unsigned*)(X + (ll)v3.x * xs + 2 * lane), f0, f1);
            wa = __int_as_float(v3.y);
            a0 = fmaf(wa, f0, a0);
            a1 = fmaf(wa, f1, a1);
        }
    }
    for (; j < je; ++j) {
        int2 v0 = ep[j];
        if (act) {
            float f0, f1;
            bf16pair(*(const unsigned*)(X + (ll)v0.x * xs + 2 * lane), f0, f1);
            float wa = __int_as_float(v0.y);
            a0 = fmaf(wa, f0, a0);
            a1 = fmaf(wa, f1, a1);
        }
    }
    float h0 = act ? fmaxf(a0 + bb0, 0.0f) : 0.0f;
    float h1 = act ? fmaxf(a1 + bb1, 0.0f) : 0.0f;
    float z0 = h0 * w00 + h1 * w10;
    float z1 = h0 * w01 + h1 * w11;
    float z2 = h0 * w02 + h1 * w12;
#pragma unroll
    for (int off = 16; off > 0; off >>= 1) {
        z0 += __shfl_xor(z0, off);
        z1 += __shfl_xor(z1, off);
        z2 += __shfl_xor(z2, off);
    }
    if (valid && lane == 0) {
        int g = ldi(batch, n, flags[1]);
        atomicMax(&lmax[g * 3 + 0], fenc(z0 + wfm[MBO + 0]));
        atomicMax(&lmax[g * 3 + 1], fenc(z1 + wfm[MBO + 1]));
        atomicMax(&lmax[g * 3 + 2], fenc(z2 + wfm[MBO + 2]));
    }
    __syncthreads();
    for (int i = threadIdx.x; i < 192; i += blockDim.x) {
        unsigned v = lmax[i];
        if (v != ENC_NEG_INF) atomicMax(&pooled[i], v);
    }
}

// ---------------- MFMA GEMM: Y = act(X @ W + b), X bf16 row-major (stride >= KC*32) -------
// wave = 16 nodes x OUT cols via mfma_f32_16x16x32_bf16. No LDS, no in-loop SMEM.
// B-frag pre-packed (k_cvt); D: col=lane&15, row=(lane>>4)*4+reg. Writeback guarded; A-row
// overreads hit finite poison x zero-padded B -> 0. #pragma unroll 1 bounds live B-frags.
template <int K, int KC, int OUT, int CT, bool RELU, bool BIAS>
__global__ __launch_bounds__(256) void k_gemm(const __hip_bfloat16* __restrict__ X, int xs,
                                              __hip_bfloat16* __restrict__ Y, int ys,
                                              const short8* __restrict__ Wp,
                                              const float* __restrict__ bias, int N) {
    const int lane = threadIdx.x & 63;
    const int wid = threadIdx.x >> 6;
    const int m0 = blockIdx.x * 64 + wid * 16;
    const int mrow = lane & 15;
    const int koct = lane >> 4;
    const __hip_bfloat16* xrow = X + (ll)(m0 + mrow) * xs + koct * 8;
    f32x4 acc[CT];
#pragma unroll
    for (int ct = 0; ct < CT; ++ct)
#pragma unroll
        for (int r = 0; r < 4; ++r) acc[ct][r] = 0.0f;
    float bv[CT];
#pragma unroll
    for (int ct = 0; ct < CT; ++ct) {
        int col = ct * 16 + mrow;
        bv[ct] = (BIAS && col < OUT) ? bias[col] : 0.0f;
    }
#pragma unroll 1
    for (int kc = 0; kc < KC; ++kc) {
        short8 a = *(const short8*)(xrow + kc * 32);
#pragma unroll
        for (int ct = 0; ct < CT; ++ct) {
            short8 b = Wp[(ct * KC + kc) * 64 + lane];
            acc[ct] = __builtin_amdgcn_mfma_f32_16x16x32_bf16(a, b, acc[ct], 0, 0, 0);
        }
    }
#pragma unroll
    for (int ct = 0; ct < CT; ++ct) {
        int col = ct * 16 + mrow;
        if (col >= OUT) continue;
#pragma unroll
        for (int r = 0; r < 4; ++r) {
            int node = m0 + koct * 4 + r;
            if (node >= N) continue;
            float v = acc[ct][r] + bv[ct];
            if (RELU) v = fmaxf(v, 0.0f);
            Y[(ll)node * ys + col] = __float2bfloat16(v);
        }
    }
}

// ---------------- softmax over [64,3] ----------------
__global__ void k_softmax(const unsigned* __restrict__ pooled, void* __restrict__ out,
                          const int* __restrict__ flags) {
    int g = threadIdx.x;
    if (g >= 64) return;
    int bf = flags[0];
    float a = fdec(pooled[g * 3 + 0]);
    float b = fdec(pooled[g * 3 + 1]);
    float c = fdec(pooled[g * 3 + 2]);
    float m = fmaxf(a, fmaxf(b, c));
    float ea = __expf(a - m), eb = __expf(b - m), ec = __expf(c - m);
    float s = 1.0f / (ea + eb + ec);
    if (bf) {
        __hip_bfloat16* o = (__hip_bfloat16*)out;
        o[g * 3 + 0] = __float2bfloat16(ea * s);
        o[g * 3 + 1] = __float2bfloat16(eb * s);
        o[g * 3 + 2] = __float2bfloat16(ec * s);
    } else {
        float* o = (float*)out;
        o[g * 3 + 0] = ea * s;
        o[g * 3 + 1] = eb * s;
        o[g * 3 + 2] = ec * s;
    }
}

extern "C" void kernel_launch(void* const* d_in, const int* in_sizes, int n_in,
                              void* d_out, int out_size, void* d_ws, size_t ws_size,
                              hipStream_t stream) {
    const void* x = d_in[0];
    const int* ei = (const int*)d_in[1];
    const int* batch = (const int*)d_in[2];

    const int N = in_sizes[0] / 36;
    const int E = in_sizes[1] / 2;

    // ---- workspace carve ----
    char* ws = (char*)d_ws;
    size_t off = 0;
    auto carve = [&](size_t bytes) {
        char* p = ws + off;
        off = (off + bytes + 255) & ~(size_t)255;
        return p;
    };
    int* flags = (int*)carve(16);
    float* wfm = (float*)carve((size_t)N_MISC * 4);
    __hip_bfloat16* wpack = (__hip_bfloat16*)carve((size_t)N_PACK * 2);
    float* dinv = (float*)carve((size_t)N * 4);
    int* cnt = (int*)carve((size_t)N * 4);
    int* rowptr = (int*)carve((size_t)(N + 1) * 4);
    int2* ep = (int2*)carve((size_t)E * 8);
    unsigned* pooled = (unsigned*)carve(768);
    const int NB = DIV_UP(N + 1, 256);  // must be <= 256 (N <= ~65k) for k_scan3 offset calc
    int* bsum = (int*)carve((size_t)NB * 4);
    // R1: A1 bf16 s64 (128B) | A2 bf16 s96 (192B) | T3 bf16 s64 (128B)
    char* R1 = carve((size_t)N * 192);
    // R2: H1 bf16 s80 (160B) | H2 bf16 s160 (320B)
    char* R2 = carve((size_t)N * 320);
    (void)carve(65536);  // pad: unguarded GEMM A-row overreads stay in workspace

    const int B = 256;
    const int GB = DIV_UP(N, 64);

    // 0. dtype detection (+cnt zero +pooled init) + weight conversion/packing
    k_detect<<<DIV_UP(N, B), B, 0, stream>>>((const unsigned*)x, (const unsigned*)ei, flags, cnt,
                                             pooled, N);
    k_cvt<<<DIV_UP(N_PACK + N_MISC, B), B, 0, stream>>>(d_in[3], d_in[4], d_in[5], d_in[6],
                                                        d_in[7], d_in[8], d_in[9], d_in[10], wpack,
                                                        wfm, flags);

    // 1. CSR build (scan2 folded into scan3's per-block offset reduce)
    k_hist<<<DIV_UP(E, B), B, 0, stream>>>(ei, cnt, flags, E);
    k_scan1<<<NB, 256, 0, stream>>>(cnt, bsum, dinv, N);
    k_scan3<<<NB, 256, 0, stream>>>(cnt, bsum, rowptr, NB, N);
    k_fill<<<DIV_UP(E, B), B, 0, stream>>>(ei, rowptr, cnt, ep, dinv, flags, E);

    // 2. layer 1: agg x (36, 2 nodes/wave) -> A1 bf16 s64; MFMA GEMM 36->75 relu -> H1 s80
    k_agg1<<<DIV_UP(N, 8), B, 0, stream>>>(x, (__hip_bfloat16*)R1, rowptr, ep, dinv, flags, N);
    k_gemm<36, 2, 75, 5, true, true><<<GB, B, 0, stream>>>(
        (const __hip_bfloat16*)R1, 64, (__hip_bfloat16*)R2, 80, (const short8*)(wpack + P1),
        wfm + MB1, N);

    // 3. layer 2: agg H1 (75 paired, 2 nodes/wave) -> A2 s96; MFMA GEMM 75->150 relu -> H2 s160
    k_aggp2<<<DIV_UP(N, 8), B, 0, stream>>>((const __hip_bfloat16*)R2, 80, (__hip_bfloat16*)R1, 96,
                                            rowptr, ep, dinv, N);
    k_gemm<75, 3, 150, 10, true, true><<<GB, B, 0, stream>>>(
        (const __hip_bfloat16*)R1, 96, (__hip_bfloat16*)R2, 160, (const short8*)(wpack + P2),
        wfm + MB2, N);

    // 4. layer 3: MFMA GEMM 150->50 -> T3 s64; fused agg+head+pool (2 nodes/wave) -> pooled
    k_gemm<150, 5, 50, 4, false, false><<<GB, B, 0, stream>>>(
        (const __hip_bfloat16*)R2, 160, (__hip_bfloat16*)R1, 64, (const short8*)(wpack + P3), wfm,
        N);
    k_agg3h<<<DIV_UP(N, 8), B, 0, stream>>>((const __hip_bfloat16*)R1, 64, rowptr, ep, dinv, wfm,
                                            batch, pooled, flags, N);

    // 5. softmax
    k_softmax<<<1, 64, 0, stream>>>(pooled, d_out, flags);
}

// Round 15
// 236.030 us; speedup vs baseline: 1.0510x; 1.0510x over previous
//
#include <hip/hip_runtime.h>
#include <hip/hip_bf16.h>

#define DIV_UP(a, b) (((a) + (b) - 1) / (b))
typedef long long ll;
typedef __attribute__((ext_vector_type(8))) short short8;
typedef __attribute__((ext_vector_type(4))) float f32x4;

// ---------- runtime-dtype helpers ----------
__device__ __forceinline__ float ldf(const void* p, ll i, int bf) {
    return bf ? __bfloat162float(((const __hip_bfloat16*)p)[i]) : ((const float*)p)[i];
}
__device__ __forceinline__ int ldi(const int* p, ll i, int w) {
    return w ? p[2 * i] : p[i];
}
// decode packed bf16 pair (little-endian: low 16 bits = even col)
__device__ __forceinline__ void bf16pair(unsigned u, float& f0, float& f1) {
    f0 = __uint_as_float(u << 16);
    f1 = __uint_as_float(u & 0xFFFF0000u);
}

// ---- ordered-uint encoding for float atomicMax ----
__device__ __forceinline__ unsigned fenc(float f) {
    unsigned u = __float_as_uint(f);
    return (u & 0x80000000u) ? ~u : (u | 0x80000000u);
}
__device__ __forceinline__ float fdec(unsigned u) {
    unsigned v = (u & 0x80000000u) ? (u & 0x7FFFFFFFu) : ~u;
    return __uint_as_float(v);
}
#define ENC_NEG_INF 0x007FFFFFu

// ---- f32 misc pool offsets ----
#define MB1 0    // b1: 75
#define MB2 80   // b2: 150
#define MHW 240  // Wo: 150
#define MB3 390  // b3: 50
#define MBO 440  // bo: 3
#define N_MISC 444
// ---- Wpack (bf16, B-fragment layout) region bases, in bf16 elements ----
#define P1 0      // L1: CT=5, KC=2 -> 5120
#define P2 5120   // L2: CT=10, KC=3 -> 15360
#define P3 20480  // L3: CT=4, KC=5 -> 10240
#define N_PACK 30720

// ---------------- dtype detection + cnt zero + pooled init (fused, grid-wide) --------------
__global__ void k_detect(const unsigned* __restrict__ xb, const unsigned* __restrict__ eb,
                         int* __restrict__ flags, int* __restrict__ cnt,
                         unsigned* __restrict__ pooled, int N) {
    int idx = blockIdx.x * 256 + threadIdx.x;
    if (idx < N) cnt[idx] = 0;
    if (blockIdx.x == 1) {
        if (threadIdx.x < 192) pooled[threadIdx.x] = ENC_NEG_INF;
        return;
    }
    if (blockIdx.x != 0) return;
    __shared__ int sv[2];
    int t = threadIdx.x;
    if (t < 2) sv[t] = 0;
    __syncthreads();
    unsigned e = (xb[t] >> 7) & 0xFFu;
    int vote = (e >= 115u && e <= 133u) ? 1 : 0;
    int zero = (eb[2 * t + 1] == 0u) ? 1 : 0;
    atomicAdd(&sv[0], vote);
    atomicAdd(&sv[1], zero);
    __syncthreads();
    if (t == 0) {
        flags[0] = (sv[0] > 128) ? 1 : 0;
        flags[1] = (sv[1] > 200) ? 1 : 0;
    }
}

// ---------------- weight conversion: MFMA B-fragment pack + misc f32 pool (fused) ---------
__global__ void k_cvt(const void* __restrict__ W1, const void* __restrict__ b1,
                      const void* __restrict__ W2, const void* __restrict__ b2,
                      const void* __restrict__ W3, const void* __restrict__ b3,
                      const void* __restrict__ Wo, const void* __restrict__ bo,
                      __hip_bfloat16* __restrict__ wp, float* __restrict__ wfm,
                      const int* __restrict__ flags) {
    int t = blockIdx.x * blockDim.x + threadIdx.x;
    int bf = flags[0];
    if (t < N_PACK) {
        const void* W;
        int i, K, OUT, KC;
        if (t < P2) {
            W = W1;
            i = t;
            K = 36;
            OUT = 75;
            KC = 2;
        } else if (t < P3) {
            W = W2;
            i = t - P2;
            K = 75;
            OUT = 150;
            KC = 3;
        } else {
            W = W3;
            i = t - P3;
            K = 150;
            OUT = 50;
            KC = 5;
        }
        int j = i & 7;
        int lane = (i >> 3) & 63;
        int tile = i >> 9;
        int kc = tile % KC;
        int ct = tile / KC;
        int k = kc * 32 + ((lane >> 4) << 3) + j;
        int col = ct * 16 + (lane & 15);
        float v = (k < K && col < OUT) ? ldf(W, (ll)k * OUT + col, bf) : 0.0f;
        wp[t] = __float2bfloat16(v);
    } else {
        int m = t - N_PACK;
        if (m >= N_MISC) return;
        float v = 0.0f;
        if (m < 75)
            v = ldf(b1, m, bf);
        else if (m >= MB2 && m < MB2 + 150)
            v = ldf(b2, m - MB2, bf);
        else if (m >= MHW && m < MHW + 150)
            v = ldf(Wo, m - MHW, bf);
        else if (m >= MB3 && m < MB3 + 50)
            v = ldf(b3, m - MB3, bf);
        else if (m >= MBO && m < MBO + 3)
            v = ldf(bo, m - MBO, bf);
        wfm[m] = v;
    }
}

// ---------------- CSR build ----------------
__global__ void k_hist(const int* __restrict__ ei, int* __restrict__ cnt,
                       const int* __restrict__ flags, int E) {
    int t = blockIdx.x * blockDim.x + threadIdx.x;
    if (t >= E) return;
    atomicAdd(&cnt[ldi(ei, (ll)E + t, flags[1])], 1);
}
__global__ void k_scan1(const int* __restrict__ cnt, int* __restrict__ bsum,
                        float* __restrict__ dinv, int N) {
    __shared__ int s[256];
    int t = threadIdx.x;
    int idx = blockIdx.x * 256 + t;
    int v = (idx < N) ? cnt[idx] : 0;
    if (idx < N) dinv[idx] = rsqrtf((float)v + 1.0f);  // +1 self-loop
    s[t] = v;
    __syncthreads();
#pragma unroll
    for (int off = 128; off > 0; off >>= 1) {
        if (t < off) s[t] += s[t + off];
        __syncthreads();
    }
    if (t == 0) bsum[blockIdx.x] = s[0];
}
// per-block: computes its own global offset from bsum (NB <= 256), local scan of cnt ->
// rowptr; re-zeroes cnt for use as k_fill cursor. (k_scan2 launch folded in, R14.)
__global__ void k_scan3(int* __restrict__ cnt, const int* __restrict__ bsum,
                        int* __restrict__ rowptr, int nb, int N) {
    __shared__ int s[256];
    int t = threadIdx.x;
    s[t] = (t < blockIdx.x && t < nb) ? bsum[t] : 0;
    __syncthreads();
#pragma unroll
    for (int off = 128; off > 0; off >>= 1) {
        if (t < off) s[t] += s[t + off];
        __syncthreads();
    }
    int offset = s[0];
    __syncthreads();
    int idx = blockIdx.x * 256 + t;
    int v = (idx < N) ? cnt[idx] : 0;
    if (idx < N) cnt[idx] = 0;
    s[t] = v;
    __syncthreads();
    for (int off = 1; off < 256; off <<= 1) {
        int o = (t >= off) ? s[t - off] : 0;
        __syncthreads();
        s[t] += o;
        __syncthreads();
    }
    if (idx <= N) rowptr[idx] = offset + s[t] - v;
}
__global__ void k_fill(const int* __restrict__ ei, const int* __restrict__ rowptr,
                       int* __restrict__ cursor, int2* __restrict__ ep,
                       const float* __restrict__ dinv, const int* __restrict__ flags, int E) {
    int t = blockIdx.x * blockDim.x + threadIdx.x;
    if (t >= E) return;
    int wi = flags[1];
    int s = ldi(ei, t, wi);
    int d = ldi(ei, (ll)E + t, wi);
    int pos = rowptr[d] + atomicAdd(&cursor[d], 1);
    int2 v;
    v.x = s;
    v.y = __float_as_int(dinv[s] * dinv[d]);
    ep[pos] = v;
}

// ---------------- layer-1 aggregation: TWO nodes per wave (half-wave = 32 lanes) ----------
__global__ void k_agg1(const void* __restrict__ X, __hip_bfloat16* __restrict__ Y,
                       const int* __restrict__ rowptr, const int2* __restrict__ ep,
                       const float* __restrict__ dinv, const int* __restrict__ flags, int N) {
    int n = blockIdx.x * 8 + (threadIdx.x >> 5);
    if (n >= N) return;
    int lane = threadIdx.x & 31;
    int bf = flags[0];
    float di = dinv[n];
    float w0 = di * di;
    int j = rowptr[n];
    int je = rowptr[n + 1];
    if (bf) {
        const __hip_bfloat16* Xb = (const __hip_bfloat16*)X;
        bool act = lane < 18;
        float a0 = 0.0f, a1 = 0.0f;
        if (act) {
            float f0, f1;
            bf16pair(*(const unsigned*)(Xb + (ll)n * 36 + 2 * lane), f0, f1);
            a0 = w0 * f0;
            a1 = w0 * f1;
        }
        for (; j + 3 < je; j += 4) {
            int2 v0 = ep[j];
            int2 v1 = ep[j + 1];
            int2 v2 = ep[j + 2];
            int2 v3 = ep[j + 3];
            if (act) {
                float f0, f1;
                bf16pair(*(const unsigned*)(Xb + (ll)v0.x * 36 + 2 * lane), f0, f1);
                float wa = __int_as_float(v0.y);
                a0 = fmaf(wa, f0, a0);
                a1 = fmaf(wa, f1, a1);
                bf16pair(*(const unsigned*)(Xb + (ll)v1.x * 36 + 2 * lane), f0, f1);
                wa = __int_as_float(v1.y);
                a0 = fmaf(wa, f0, a0);
                a1 = fmaf(wa, f1, a1);
                bf16pair(*(const unsigned*)(Xb + (ll)v2.x * 36 + 2 * lane), f0, f1);
                wa = __int_as_float(v2.y);
                a0 = fmaf(wa, f0, a0);
                a1 = fmaf(wa, f1, a1);
                bf16pair(*(const unsigned*)(Xb + (ll)v3.x * 36 + 2 * lane), f0, f1);
                wa = __int_as_float(v3.y);
                a0 = fmaf(wa, f0, a0);
                a1 = fmaf(wa, f1, a1);
            }
        }
        for (; j < je; ++j) {
            int2 v0 = ep[j];
            if (act) {
                float f0, f1;
                bf16pair(*(const unsigned*)(Xb + (ll)v0.x * 36 + 2 * lane), f0, f1);
                float wa = __int_as_float(v0.y);
                a0 = fmaf(wa, f0, a0);
                a1 = fmaf(wa, f1, a1);
            }
        }
        if (act) {
            __hip_bfloat162 h;
            h.x = __float2bfloat16(a0);
            h.y = __float2bfloat16(a1);
            *(__hip_bfloat162*)(Y + (ll)n * 64 + 2 * lane) = h;
        }
    } else {
        const float* Xf = (const float*)X;
        bool act2 = lane < 4;
        float a0 = w0 * Xf[(ll)n * 36 + lane];
        float a1 = act2 ? w0 * Xf[(ll)n * 36 + 32 + lane] : 0.0f;
        for (; j + 3 < je; j += 4) {
            int2 v0 = ep[j];
            int2 v1 = ep[j + 1];
            int2 v2 = ep[j + 2];
            int2 v3 = ep[j + 3];
            float wa = __int_as_float(v0.y);
            a0 = fmaf(wa, Xf[(ll)v0.x * 36 + lane], a0);
            if (act2) a1 = fmaf(wa, Xf[(ll)v0.x * 36 + 32 + lane], a1);
            wa = __int_as_float(v1.y);
            a0 = fmaf(wa, Xf[(ll)v1.x * 36 + lane], a0);
            if (act2) a1 = fmaf(wa, Xf[(ll)v1.x * 36 + 32 + lane], a1);
            wa = __int_as_float(v2.y);
            a0 = fmaf(wa, Xf[(ll)v2.x * 36 + lane], a0);
            if (act2) a1 = fmaf(wa, Xf[(ll)v2.x * 36 + 32 + lane], a1);
            wa = __int_as_float(v3.y);
            a0 = fmaf(wa, Xf[(ll)v3.x * 36 + lane], a0);
            if (act2) a1 = fmaf(wa, Xf[(ll)v3.x * 36 + 32 + lane], a1);
        }
        for (; j < je; ++j) {
            int2 v0 = ep[j];
            float wa = __int_as_float(v0.y);
            a0 = fmaf(wa, Xf[(ll)v0.x * 36 + lane], a0);
            if (act2) a1 = fmaf(wa, Xf[(ll)v0.x * 36 + 32 + lane], a1);
        }
        Y[(ll)n * 64 + lane] = __float2bfloat16(a0);
        if (act2) Y[(ll)n * 64 + 32 + lane] = __float2bfloat16(a1);
    }
}

// ---------------- layer-2 paired aggregation: TWO nodes per wave ----------------
__global__ void k_aggp2(const __hip_bfloat16* __restrict__ X, int xs,
                        __hip_bfloat16* __restrict__ Y, int ys, const int* __restrict__ rowptr,
                        const int2* __restrict__ ep, const float* __restrict__ dinv, int N) {
    int n = blockIdx.x * 8 + (threadIdx.x >> 5);
    if (n >= N) return;
    int lane = threadIdx.x & 31;
    bool act2 = lane < 6;  // pairs 32..37
    float di = dinv[n];
    float w0 = di * di;
    float a0, a1, b0 = 0.0f, b1 = 0.0f;
    {
        float f0, f1;
        bf16pair(*(const unsigned*)(X + (ll)n * xs + 2 * lane), f0, f1);
        a0 = w0 * f0;
        a1 = w0 * f1;
        if (act2) {
            bf16pair(*(const unsigned*)(X + (ll)n * xs + 64 + 2 * lane), f0, f1);
            b0 = w0 * f0;
            b1 = w0 * f1;
        }
    }
    int j = rowptr[n];
    int je = rowptr[n + 1];
    for (; j + 1 < je; j += 2) {
        int2 v0 = ep[j];
        int2 v1 = ep[j + 1];
        float wa = __int_as_float(v0.y), wb = __int_as_float(v1.y);
        float f0, f1;
        bf16pair(*(const unsigned*)(X + (ll)v0.x * xs + 2 * lane), f0, f1);
        a0 = fmaf(wa, f0, a0);
        a1 = fmaf(wa, f1, a1);
        bf16pair(*(const unsigned*)(X + (ll)v1.x * xs + 2 * lane), f0, f1);
        a0 = fmaf(wb, f0, a0);
        a1 = fmaf(wb, f1, a1);
        if (act2) {
            bf16pair(*(const unsigned*)(X + (ll)v0.x * xs + 64 + 2 * lane), f0, f1);
            b0 = fmaf(wa, f0, b0);
            b1 = fmaf(wa, f1, b1);
            bf16pair(*(const unsigned*)(X + (ll)v1.x * xs + 64 + 2 * lane), f0, f1);
            b0 = fmaf(wb, f0, b0);
            b1 = fmaf(wb, f1, b1);
        }
    }
    if (j < je) {
        int2 v0 = ep[j];
        float wa = __int_as_float(v0.y);
        float f0, f1;
        bf16pair(*(const unsigned*)(X + (ll)v0.x * xs + 2 * lane), f0, f1);
        a0 = fmaf(wa, f0, a0);
        a1 = fmaf(wa, f1, a1);
        if (act2) {
            bf16pair(*(const unsigned*)(X + (ll)v0.x * xs + 64 + 2 * lane), f0, f1);
            b0 = fmaf(wa, f0, b0);
            b1 = fmaf(wa, f1, b1);
        }
    }
    __hip_bfloat162 h;
    h.x = __float2bfloat16(a0);
    h.y = __float2bfloat16(a1);
    *(__hip_bfloat162*)(Y + (ll)n * ys + 2 * lane) = h;
    if (act2) {
        h.x = __float2bfloat16(b0);
        h.y = __float2bfloat16(b1);
        *(__hip_bfloat162*)(Y + (ll)n * ys + 64 + 2 * lane) = h;
    }
}

// ---------------- fused layer-3 aggregation + head: T3 -> zbuf[n,3] ----------------
// TWO nodes per wave; NO block barrier after the gather (R14 lesson: fusing the pooled
// atomicMax here adds a __syncthreads that couples 8 nodes to the block's slowest edge
// list - a tail tax on a latency-bound kernel; separate k_pool is faster).
__global__ void k_agg3h(const __hip_bfloat16* __restrict__ X, int xs, float* __restrict__ zb,
                        const int* __restrict__ rowptr, const int2* __restrict__ ep,
                        const float* __restrict__ dinv, const float* __restrict__ wfm, int N) {
    int n = blockIdx.x * 8 + (threadIdx.x >> 5);
    if (n >= N) return;
    int lane = threadIdx.x & 31;
    bool act = lane < 25;
    int c0 = 2 * lane;
    float w00 = 0, w01 = 0, w02 = 0, w10 = 0, w11 = 0, w12 = 0, bb0 = 0, bb1 = 0;
    if (act) {
        w00 = wfm[MHW + c0 * 3 + 0];
        w01 = wfm[MHW + c0 * 3 + 1];
        w02 = wfm[MHW + c0 * 3 + 2];
        w10 = wfm[MHW + c0 * 3 + 3];
        w11 = wfm[MHW + c0 * 3 + 4];
        w12 = wfm[MHW + c0 * 3 + 5];
        bb0 = wfm[MB3 + c0];
        bb1 = wfm[MB3 + c0 + 1];
    }
    float di = dinv[n];
    float w0 = di * di;
    float a0 = 0.0f, a1 = 0.0f;
    if (act) {
        float f0, f1;
        bf16pair(*(const unsigned*)(X + (ll)n * xs + 2 * lane), f0, f1);
        a0 = w0 * f0;
        a1 = w0 * f1;
    }
    int j = rowptr[n];
    int je = rowptr[n + 1];
    for (; j + 3 < je; j += 4) {
        int2 v0 = ep[j];
        int2 v1 = ep[j + 1];
        int2 v2 = ep[j + 2];
        int2 v3 = ep[j + 3];
        if (act) {
            float f0, f1;
            bf16pair(*(const unsigned*)(X + (ll)v0.x * xs + 2 * lane), f0, f1);
            float wa = __int_as_float(v0.y);
            a0 = fmaf(wa, f0, a0);
            a1 = fmaf(wa, f1, a1);
            bf16pair(*(const unsigned*)(X + (ll)v1.x * xs + 2 * lane), f0, f1);
            wa = __int_as_float(v1.y);
            a0 = fmaf(wa, f0, a0);
            a1 = fmaf(wa, f1, a1);
            bf16pair(*(const unsigned*)(X + (ll)v2.x * xs + 2 * lane), f0, f1);
            wa = __int_as_float(v2.y);
            a0 = fmaf(wa, f0, a0);
            a1 = fmaf(wa, f1, a1);
            bf16pair(*(const unsigned*)(X + (ll)v3.x * xs + 2 * lane), f0, f1);
            wa = __int_as_float(v3.y);
            a0 = fmaf(wa, f0, a0);
            a1 = fmaf(wa, f1, a1);
        }
    }
    for (; j < je; ++j) {
        int2 v0 = ep[j];
        if (act) {
            float f0, f1;
            bf16pair(*(const unsigned*)(X + (ll)v0.x * xs + 2 * lane), f0, f1);
            float wa = __int_as_float(v0.y);
            a0 = fmaf(wa, f0, a0);
            a1 = fmaf(wa, f1, a1);
        }
    }
    float h0 = act ? fmaxf(a0 + bb0, 0.0f) : 0.0f;
    float h1 = act ? fmaxf(a1 + bb1, 0.0f) : 0.0f;
    float z0 = h0 * w00 + h1 * w10;
    float z1 = h0 * w01 + h1 * w11;
    float z2 = h0 * w02 + h1 * w12;
#pragma unroll
    for (int off = 16; off > 0; off >>= 1) {
        z0 += __shfl_xor(z0, off);
        z1 += __shfl_xor(z1, off);
        z2 += __shfl_xor(z2, off);
    }
    if (lane == 0) {
        zb[(ll)n * 3 + 0] = z0 + wfm[MBO + 0];
        zb[(ll)n * 3 + 1] = z1 + wfm[MBO + 1];
        zb[(ll)n * 3 + 2] = z2 + wfm[MBO + 2];
    }
}

// ---------------- MFMA GEMM: Y = act(X @ W + b), X bf16 row-major (stride >= KC*32) -------
// wave = 16 nodes x OUT cols via mfma_f32_16x16x32_bf16. No LDS, no in-loop SMEM.
// B-frag pre-packed (k_cvt); D: col=lane&15, row=(lane>>4)*4+reg. Writeback guarded; A-row
// overreads hit finite poison x zero-padded B -> 0. #pragma unroll 1 bounds live B-frags.
template <int K, int KC, int OUT, int CT, bool RELU, bool BIAS>
__global__ __launch_bounds__(256) void k_gemm(const __hip_bfloat16* __restrict__ X, int xs,
                                              __hip_bfloat16* __restrict__ Y, int ys,
                                              const short8* __restrict__ Wp,
                                              const float* __restrict__ bias, int N) {
    const int lane = threadIdx.x & 63;
    const int wid = threadIdx.x >> 6;
    const int m0 = blockIdx.x * 64 + wid * 16;
    const int mrow = lane & 15;
    const int koct = lane >> 4;
    const __hip_bfloat16* xrow = X + (ll)(m0 + mrow) * xs + koct * 8;
    f32x4 acc[CT];
#pragma unroll
    for (int ct = 0; ct < CT; ++ct)
#pragma unroll
        for (int r = 0; r < 4; ++r) acc[ct][r] = 0.0f;
    float bv[CT];
#pragma unroll
    for (int ct = 0; ct < CT; ++ct) {
        int col = ct * 16 + mrow;
        bv[ct] = (BIAS && col < OUT) ? bias[col] : 0.0f;
    }
#pragma unroll 1
    for (int kc = 0; kc < KC; ++kc) {
        short8 a = *(const short8*)(xrow + kc * 32);
#pragma unroll
        for (int ct = 0; ct < CT; ++ct) {
            short8 b = Wp[(ct * KC + kc) * 64 + lane];
            acc[ct] = __builtin_amdgcn_mfma_f32_16x16x32_bf16(a, b, acc[ct], 0, 0, 0);
        }
    }
#pragma unroll
    for (int ct = 0; ct < CT; ++ct) {
        int col = ct * 16 + mrow;
        if (col >= OUT) continue;
#pragma unroll
        for (int r = 0; r < 4; ++r) {
            int node = m0 + koct * 4 + r;
            if (node >= N) continue;
            float v = acc[ct][r] + bv[ct];
            if (RELU) v = fmaxf(v, 0.0f);
            Y[(ll)node * ys + col] = __float2bfloat16(v);
        }
    }
}

// ---------------- pool: segment-max of zbuf into pooled (hierarchical) ----------------
__global__ void k_pool(const float* __restrict__ zb, const int* __restrict__ batch,
                       unsigned* __restrict__ pooled, const int* __restrict__ flags, int N) {
    __shared__ unsigned lmax[192];
    int wi = flags[1];
    for (int i = threadIdx.x; i < 192; i += blockDim.x) lmax[i] = ENC_NEG_INF;
    __syncthreads();
    int n = blockIdx.x * blockDim.x + threadIdx.x;
    int lane = threadIdx.x & 63;
    float z0 = -3.4e38f, z1 = -3.4e38f, z2 = -3.4e38f;
    int g = 0;
    if (n < N) {
        z0 = zb[(ll)n * 3 + 0];
        z1 = zb[(ll)n * 3 + 1];
        z2 = zb[(ll)n * 3 + 2];
        g = ldi(batch, n, wi);
    }
    int g0 = __shfl(g, 0);
    unsigned long long uni = __ballot(n < N && g == g0);
    if (uni == ~0ULL) {
#pragma unroll
        for (int off = 32; off > 0; off >>= 1) {
            z0 = fmaxf(z0, __shfl_xor(z0, off));
            z1 = fmaxf(z1, __shfl_xor(z1, off));
            z2 = fmaxf(z2, __shfl_xor(z2, off));
        }
        if (lane == 0) {
            atomicMax(&lmax[g0 * 3 + 0], fenc(z0));
            atomicMax(&lmax[g0 * 3 + 1], fenc(z1));
            atomicMax(&lmax[g0 * 3 + 2], fenc(z2));
        }
    } else if (n < N) {
        atomicMax(&lmax[g * 3 + 0], fenc(z0));
        atomicMax(&lmax[g * 3 + 1], fenc(z1));
        atomicMax(&lmax[g * 3 + 2], fenc(z2));
    }
    __syncthreads();
    for (int i = threadIdx.x; i < 192; i += blockDim.x) {
        unsigned v = lmax[i];
        if (v != ENC_NEG_INF) atomicMax(&pooled[i], v);
    }
}

// ---------------- softmax over [64,3] ----------------
__global__ void k_softmax(const unsigned* __restrict__ pooled, void* __restrict__ out,
                          const int* __restrict__ flags) {
    int g = threadIdx.x;
    if (g >= 64) return;
    int bf = flags[0];
    float a = fdec(pooled[g * 3 + 0]);
    float b = fdec(pooled[g * 3 + 1]);
    float c = fdec(pooled[g * 3 + 2]);
    float m = fmaxf(a, fmaxf(b, c));
    float ea = __expf(a - m), eb = __expf(b - m), ec = __expf(c - m);
    float s = 1.0f / (ea + eb + ec);
    if (bf) {
        __hip_bfloat16* o = (__hip_bfloat16*)out;
        o[g * 3 + 0] = __float2bfloat16(ea * s);
        o[g * 3 + 1] = __float2bfloat16(eb * s);
        o[g * 3 + 2] = __float2bfloat16(ec * s);
    } else {
        float* o = (float*)out;
        o[g * 3 + 0] = ea * s;
        o[g * 3 + 1] = eb * s;
        o[g * 3 + 2] = ec * s;
    }
}

extern "C" void kernel_launch(void* const* d_in, const int* in_sizes, int n_in,
                              void* d_out, int out_size, void* d_ws, size_t ws_size,
                              hipStream_t stream) {
    const void* x = d_in[0];
    const int* ei = (const int*)d_in[1];
    const int* batch = (const int*)d_in[2];

    const int N = in_sizes[0] / 36;
    const int E = in_sizes[1] / 2;

    // ---- workspace carve ----
    char* ws = (char*)d_ws;
    size_t off = 0;
    auto carve = [&](size_t bytes) {
        char* p = ws + off;
        off = (off + bytes + 255) & ~(size_t)255;
        return p;
    };
    int* flags = (int*)carve(16);
    float* wfm = (float*)carve((size_t)N_MISC * 4);
    __hip_bfloat16* wpack = (__hip_bfloat16*)carve((size_t)N_PACK * 2);
    float* dinv = (float*)carve((size_t)N * 4);
    int* cnt = (int*)carve((size_t)N * 4);
    int* rowptr = (int*)carve((size_t)(N + 1) * 4);
    int2* ep = (int2*)carve((size_t)E * 8);
    unsigned* pooled = (unsigned*)carve(768);
    const int NB = DIV_UP(N + 1, 256);  // must be <= 256 for k_scan3 offset calc
    int* bsum = (int*)carve((size_t)NB * 4);
    float* zbuf = (float*)carve((size_t)N * 12);
    // R1: A1 bf16 s64 (128B) | A2 bf16 s96 (192B) | T3 bf16 s64 (128B)
    char* R1 = carve((size_t)N * 192);
    // R2: H1 bf16 s80 (160B) | H2 bf16 s160 (320B)
    char* R2 = carve((size_t)N * 320);
    (void)carve(65536);  // pad: unguarded GEMM A-row overreads stay in workspace

    const int B = 256;
    const int GB = DIV_UP(N, 64);

    // 0. dtype detection (+cnt zero +pooled init) + weight conversion/packing
    k_detect<<<DIV_UP(N, B), B, 0, stream>>>((const unsigned*)x, (const unsigned*)ei, flags, cnt,
                                             pooled, N);
    k_cvt<<<DIV_UP(N_PACK + N_MISC, B), B, 0, stream>>>(d_in[3], d_in[4], d_in[5], d_in[6],
                                                        d_in[7], d_in[8], d_in[9], d_in[10], wpack,
                                                        wfm, flags);

    // 1. CSR build
    k_hist<<<DIV_UP(E, B), B, 0, stream>>>(ei, cnt, flags, E);
    k_scan1<<<NB, 256, 0, stream>>>(cnt, bsum, dinv, N);
    k_scan3<<<NB, 256, 0, stream>>>(cnt, bsum, rowptr, NB, N);
    k_fill<<<DIV_UP(E, B), B, 0, stream>>>(ei, rowptr, cnt, ep, dinv, flags, E);

    // 2. layer 1: agg x (36, 2 nodes/wave) -> A1 bf16 s64; MFMA GEMM 36->75 relu -> H1 s80
    k_agg1<<<DIV_UP(N, 8), B, 0, stream>>>(x, (__hip_bfloat16*)R1, rowptr, ep, dinv, flags, N);
    k_gemm<36, 2, 75, 5, true, true><<<GB, B, 0, stream>>>(
        (const __hip_bfloat16*)R1, 64, (__hip_bfloat16*)R2, 80, (const short8*)(wpack + P1),
        wfm + MB1, N);

    // 3. layer 2: agg H1 (75 paired, 2 nodes/wave) -> A2 s96; MFMA GEMM 75->150 relu -> H2 s160
    k_aggp2<<<DIV_UP(N, 8), B, 0, stream>>>((const __hip_bfloat16*)R2, 80, (__hip_bfloat16*)R1, 96,
                                            rowptr, ep, dinv, N);
    k_gemm<75, 3, 150, 10, true, true><<<GB, B, 0, stream>>>(
        (const __hip_bfloat16*)R1, 96, (__hip_bfloat16*)R2, 160, (const short8*)(wpack + P2),
        wfm + MB2, N);

    // 4. layer 3: MFMA GEMM 150->50 -> T3 s64; fused agg+head (2 nodes/wave) -> zbuf[N,3]
    k_gemm<150, 5, 50, 4, false, false><<<GB, B, 0, stream>>>(
        (const __hip_bfloat16*)R2, 160, (__hip_bfloat16*)R1, 64, (const short8*)(wpack + P3), wfm,
        N);
    k_agg3h<<<DIV_UP(N, 8), B, 0, stream>>>((const __hip_bfloat16*)R1, 64, zbuf, rowptr, ep, dinv,
                                            wfm, N);

    // 5. pooling + softmax
    k_pool<<<DIV_UP(N, B), B, 0, stream>>>(zbuf, batch, pooled, flags, N);
    k_softmax<<<1, 64, 0, stream>>>(pooled, d_out, flags);
}